// Round 1
// baseline (427.889 us; speedup 1.0000x reference)
//
#include <hip/hip_runtime.h>

typedef __bf16 bf16x8 __attribute__((ext_vector_type(8)));
typedef float f32x4 __attribute__((ext_vector_type(4)));

__device__ __forceinline__ unsigned short f2bf(float f) {
    unsigned int u = __builtin_bit_cast(unsigned int, f);
    u += 0x7fffu + ((u >> 16) & 1u);
    return (unsigned short)(u >> 16);
}

// XOR swizzle for 1024B-row LDS tiles: byte ^= ((row&7)<<4), row = byte>>10
__device__ __forceinline__ unsigned swz1k(unsigned byte) {
    return byte ^ ((byte >> 6) & 0x70u);
}

// ---------------- K1: P = (Wq^T Wk) in k-chunked layout Pc[kc][j][32] (bf16),
// Pc[kc][j][t] = sum_e Wk[e][j] * Wq[e][kc*32+t]   ( = M[d][j], d = kc*32+t )
// plus Wv -> bf16 copy.
__global__ __launch_bounds__(256) void prep_kernel(
    const float* __restrict__ Wq, const float* __restrict__ Wk,
    const float* __restrict__ Wv, unsigned short* __restrict__ Pc,
    unsigned short* __restrict__ Wvb)
{
    int b = blockIdx.x;
    if (b < 1024) {
        int j0 = (b >> 4) * 8;
        int kc = b & 15;
        int jloc = threadIdx.x >> 5;
        int t = threadIdx.x & 31;
        int j = j0 + jloc, d = kc * 32 + t;
        float acc = 0.f;
        #pragma unroll 8
        for (int e = 0; e < 512; ++e)
            acc = fmaf(Wk[e * 512 + j], Wq[e * 512 + d], acc);
        Pc[((kc * 512) + j) * 32 + t] = f2bf(acc);
    } else {
        int i = (b - 1024) * 256 + (int)threadIdx.x;
        Wvb[i] = f2bf(Wv[i]);
    }
}

// ---------------- K2: fused main kernel. 1 block = 4 batches = 64 H rows.
// Phase 1: H f32 -> bf16 LDS (swizzled)
// Phase 2: T = Hbf @ P^T  (64x512, MFMA, dbuf'd P chunks)  -> bf16 LDS
// Phase 3: scores_b = T_b @ H_b^T / sqrt(d) + log(F+eps)   (MFMA, waves 0-3)
// Phase 4: softmax rows; w[k] = sum_q F[q] alpha[q][k]
// Phase 5: out = sum_k F[k] H[k,:] (fp32 residual-pool);  g = sum_k w[k] H[k,:] (bf16)
__global__ __launch_bounds__(512) void attn_main_kernel(
    const float* __restrict__ H, const float* __restrict__ F,
    const unsigned short* __restrict__ Pc,
    float* __restrict__ out, unsigned short* __restrict__ g_ws)
{
    extern __shared__ char smem[];
    char* HBF = smem;                        // 64 rows x 1024B, swizzled (64 KB)
    char* MB0 = smem + 65536;                // 512 rows x 80B (40 KB)
    char* MB1 = smem + 106496;               // 512 rows x 80B (40 KB)
    char* TBF = smem + 65536;                // alias over MB: 64 x 1024B swizzled
    float* wbuf = (float*)(smem + 147456);   // [4][16]

    const int tid = threadIdx.x;
    const int wv = tid >> 6;
    const int ln = tid & 63;
    const int rl = ln & 15;   // fragment row/col within tile
    const int kg = ln >> 4;   // k-group 0..3
    const long long gr0 = (long long)blockIdx.x * 64;

    // ---- Phase 1: stage H (fp32 global, coalesced) -> bf16 swizzled LDS
    {
        const float4* src = (const float4*)(H + gr0 * 512);
        #pragma unroll
        for (int rep = 0; rep < 16; ++rep) {
            int idx = rep * 512 + tid;                 // float4 index in [0,8192)
            float4 v = src[idx];
            ushort4 bv;
            bv.x = f2bf(v.x); bv.y = f2bf(v.y); bv.z = f2bf(v.z); bv.w = f2bf(v.w);
            unsigned byte = (unsigned)(idx >> 7) * 1024u + (unsigned)(idx & 127) * 8u;
            *(ushort4*)(HBF + swz1k(byte)) = bv;
        }
    }

    // ---- Phase 2: T-GEMM with double-buffered P chunks
    uint4 stg[4];
    {
        const uint4* p = (const uint4*)(Pc);
        #pragma unroll
        for (int q = 0; q < 4; ++q) stg[q] = p[tid * 4 + q];
        #pragma unroll
        for (int q = 0; q < 4; ++q) *(uint4*)(MB0 + tid * 80 + q * 16) = stg[q];
    }
    f32x4 acc[4][4];
    #pragma unroll
    for (int i = 0; i < 4; ++i)
        #pragma unroll
        for (int jj = 0; jj < 4; ++jj)
            acc[i][jj] = f32x4{0.f, 0.f, 0.f, 0.f};

    for (int kc = 0; kc < 16; ++kc) {
        if (kc < 15) {
            const uint4* p = (const uint4*)(Pc + (kc + 1) * 16384);
            #pragma unroll
            for (int q = 0; q < 4; ++q) stg[q] = p[tid * 4 + q];
        }
        __syncthreads();
        char* mb = (kc & 1) ? MB1 : MB0;
        bf16x8 a[4], bfr[4];
        #pragma unroll
        for (int i = 0; i < 4; ++i) {
            unsigned off = (unsigned)(i * 16 + rl) * 1024u + (unsigned)kc * 64u + (unsigned)kg * 16u;
            a[i] = *(bf16x8*)(HBF + swz1k(off));
        }
        #pragma unroll
        for (int jj = 0; jj < 4; ++jj) {
            int j = wv * 64 + jj * 16 + rl;
            bfr[jj] = *(bf16x8*)(mb + j * 80 + kg * 16);
        }
        #pragma unroll
        for (int i = 0; i < 4; ++i)
            #pragma unroll
            for (int jj = 0; jj < 4; ++jj)
                acc[i][jj] = __builtin_amdgcn_mfma_f32_16x16x32_bf16(a[i], bfr[jj], acc[i][jj], 0, 0, 0);
        if (kc < 15) {
            char* mbn = (kc & 1) ? MB0 : MB1;
            #pragma unroll
            for (int q = 0; q < 4; ++q) *(uint4*)(mbn + tid * 80 + q * 16) = stg[q];
        }
    }
    __syncthreads();
    // write T (bf16, swizzled rows of 1024B) into TBF (C layout: row=(l>>4)*4+p, col=l&15)
    #pragma unroll
    for (int i = 0; i < 4; ++i)
        #pragma unroll
        for (int jj = 0; jj < 4; ++jj)
            #pragma unroll
            for (int p = 0; p < 4; ++p) {
                unsigned row = (unsigned)(i * 16 + kg * 4 + p);
                unsigned col = (unsigned)(wv * 64 + jj * 16 + rl);
                *(unsigned short*)(TBF + swz1k(row * 1024u + col * 2u)) = f2bf(acc[i][jj][p]);
            }
    __syncthreads();

    // ---- Phase 3+4: scores, softmax, w  (one wave per batch; waves 4-7 idle)
    if (wv < 4) {
        f32x4 sc = f32x4{0.f, 0.f, 0.f, 0.f};
        #pragma unroll
        for (int kc = 0; kc < 16; ++kc) {
            unsigned off = (unsigned)(wv * 16 + rl) * 1024u + (unsigned)kc * 64u + (unsigned)kg * 16u;
            bf16x8 aT = *(bf16x8*)(TBF + swz1k(off));
            bf16x8 bH = *(bf16x8*)(HBF + swz1k(off));   // H rows fed as B-operand == H^T
            sc = __builtin_amdgcn_mfma_f32_16x16x32_bf16(aT, bH, sc, 0, 0, 0);
        }
        const long long Bg = (long long)blockIdx.x * 4 + wv;
        const float* Fb = F + Bg * 16;
        float bias = logf(Fb[rl] + 1e-8f);              // bias for key column rl
        float alpha[4];
        #pragma unroll
        for (int p = 0; p < 4; ++p) {
            float s = sc[p] * 0.044194173824159216f + bias;  // 1/sqrt(512)
            float m = s;
            m = fmaxf(m, __shfl_xor(m, 8));
            m = fmaxf(m, __shfl_xor(m, 4));
            m = fmaxf(m, __shfl_xor(m, 2));
            m = fmaxf(m, __shfl_xor(m, 1));
            float e = expf(s - m);
            float sum = e;
            sum += __shfl_xor(sum, 8);
            sum += __shfl_xor(sum, 4);
            sum += __shfl_xor(sum, 2);
            sum += __shfl_xor(sum, 1);
            alpha[p] = e / sum;
        }
        float part = 0.f;
        #pragma unroll
        for (int p = 0; p < 4; ++p) part += Fb[kg * 4 + p] * alpha[p];
        part += __shfl_xor(part, 16);
        part += __shfl_xor(part, 32);
        if (ln < 16) wbuf[wv * 16 + ln] = part;
    }
    __syncthreads();

    // ---- Phase 5: residual pool (fp32) + g (bf16). 8 waves = 4 batches x 2 d-halves.
    {
        int bb = wv >> 1, dh = wv & 1;
        const long long Bg = (long long)blockIdx.x * 4 + bb;
        int d0 = dh * 256 + ln * 4;
        const float* Hb = H + Bg * 8192;
        const float* Fb = F + Bg * 16;
        float ox = 0.f, oy = 0.f, oz = 0.f, ow = 0.f;
        float gx = 0.f, gy = 0.f, gz = 0.f, gw = 0.f;
        #pragma unroll
        for (int k = 0; k < 16; ++k) {
            float4 h = *(const float4*)(Hb + k * 512 + d0);
            float fk = Fb[k];
            float wk = wbuf[bb * 16 + k];
            ox = fmaf(fk, h.x, ox); oy = fmaf(fk, h.y, oy);
            oz = fmaf(fk, h.z, oz); ow = fmaf(fk, h.w, ow);
            gx = fmaf(wk, h.x, gx); gy = fmaf(wk, h.y, gy);
            gz = fmaf(wk, h.z, gz); gw = fmaf(wk, h.w, gw);
        }
        float4 o4; o4.x = ox; o4.y = oy; o4.z = oz; o4.w = ow;
        *(float4*)(out + Bg * 512 + d0) = o4;
        ushort4 g4; g4.x = f2bf(gx); g4.y = f2bf(gy); g4.z = f2bf(gz); g4.w = f2bf(gw);
        *(ushort4*)(g_ws + Bg * 512 + d0) = g4;
    }
}

// ---------------- K3: out += g @ Wv^T   (8192x512 @ 512x512, bf16 MFMA)
__global__ __launch_bounds__(256) void out_gemm_kernel(
    const unsigned short* __restrict__ g_ws,
    const unsigned short* __restrict__ Wvb,
    float* __restrict__ out)
{
    extern __shared__ char smem[];  // 32 KB: 32 rows x 1024B, swizzled
    const int tid = threadIdx.x;
    const int wv = tid >> 6, ln = tid & 63;
    const int rl = ln & 15, kg = ln >> 4;
    const long long r0 = (long long)blockIdx.x * 32;
    {
        const uint4* src = (const uint4*)(g_ws + r0 * 512);
        #pragma unroll
        for (int q = 0; q < 8; ++q) {
            int idx = q * 256 + tid;
            *(uint4*)(smem + swz1k((unsigned)idx * 16u)) = src[idx];
        }
    }
    __syncthreads();
    f32x4 acc[2][8];
    #pragma unroll
    for (int i = 0; i < 2; ++i)
        #pragma unroll
        for (int jj = 0; jj < 8; ++jj)
            acc[i][jj] = f32x4{0.f, 0.f, 0.f, 0.f};
    for (int kc = 0; kc < 16; ++kc) {
        bf16x8 a[2];
        #pragma unroll
        for (int i = 0; i < 2; ++i) {
            unsigned off = (unsigned)(i * 16 + rl) * 1024u + (unsigned)kc * 64u + (unsigned)kg * 16u;
            a[i] = *(bf16x8*)(smem + swz1k(off));
        }
        bf16x8 bfr[8];
        #pragma unroll
        for (int jj = 0; jj < 8; ++jj) {
            int n = wv * 128 + jj * 16 + rl;
            bfr[jj] = *(const bf16x8*)(Wvb + n * 512 + kc * 32 + kg * 8);  // Wv[n][k] row-major
        }
        #pragma unroll
        for (int i = 0; i < 2; ++i)
            #pragma unroll
            for (int jj = 0; jj < 8; ++jj)
                acc[i][jj] = __builtin_amdgcn_mfma_f32_16x16x32_bf16(a[i], bfr[jj], acc[i][jj], 0, 0, 0);
    }
    #pragma unroll
    for (int i = 0; i < 2; ++i)
        #pragma unroll
        for (int jj = 0; jj < 8; ++jj)
            #pragma unroll
            for (int p = 0; p < 4; ++p) {
                int row = i * 16 + kg * 4 + p;
                int col = wv * 128 + jj * 16 + rl;
                out[(r0 + row) * 512 + col] += acc[i][jj][p];
            }
}

extern "C" void kernel_launch(void* const* d_in, const int* in_sizes, int n_in,
                              void* d_out, int out_size, void* d_ws, size_t ws_size,
                              hipStream_t stream)
{
    const float* H  = (const float*)d_in[0];
    const float* F  = (const float*)d_in[1];
    const float* Wq = (const float*)d_in[2];
    const float* Wk = (const float*)d_in[3];
    const float* Wv = (const float*)d_in[4];
    float* out = (float*)d_out;

    unsigned short* Pc  = (unsigned short*)d_ws;       // 16*512*32   = 262144 bf16
    unsigned short* Wvb = Pc + 262144;                 // 512*512     = 262144 bf16
    unsigned short* g   = Wvb + 262144;                // 8192*512    = 4194304 bf16
    (void)in_sizes; (void)n_in; (void)out_size; (void)ws_size;

    hipLaunchKernelGGL(prep_kernel, dim3(2048), dim3(256), 0, stream, Wq, Wk, Wv, Pc, Wvb);
    hipLaunchKernelGGL(attn_main_kernel, dim3(2048), dim3(512), 147712, stream, H, F, Pc, out, g);
    hipLaunchKernelGGL(out_gemm_kernel, dim3(256), dim3(256), 32768, stream, g, Wvb, out);
}

// Round 2
// 202.377 us; speedup vs baseline: 2.1143x; 2.1143x over previous
//
#include <hip/hip_runtime.h>

typedef __bf16 bf16x8 __attribute__((ext_vector_type(8)));
typedef float f32x4 __attribute__((ext_vector_type(4)));

__device__ __forceinline__ unsigned short f2bf(float f) {
    unsigned int u = __builtin_bit_cast(unsigned int, f);
    u += 0x7fffu + ((u >> 16) & 1u);
    return (unsigned short)(u >> 16);
}
__device__ __forceinline__ float bf2f(unsigned short u) {
    return __builtin_bit_cast(float, (unsigned)u << 16);
}

// XOR swizzle for 1024B-row LDS tiles: byte ^= ((row&7)<<4)
__device__ __forceinline__ unsigned swz1k(unsigned byte) {
    return byte ^ ((byte >> 6) & 0x70u);
}

// ---------------- K1: Pc[kc][j][t] = M[kc*32+t][j], M = Wq^T Wk  (bf16)
// plus Wv -> bf16 copy.
__global__ __launch_bounds__(256) void prep_kernel(
    const float* __restrict__ Wq, const float* __restrict__ Wk,
    const float* __restrict__ Wv, unsigned short* __restrict__ Pc,
    unsigned short* __restrict__ Wvb)
{
    int b = blockIdx.x;
    if (b < 1024) {
        int j0 = (b >> 4) * 8;
        int kc = b & 15;
        int jloc = threadIdx.x >> 5;
        int t = threadIdx.x & 31;
        int j = j0 + jloc, d = kc * 32 + t;
        float acc = 0.f;
        #pragma unroll 8
        for (int e = 0; e < 512; ++e)
            acc = fmaf(Wk[e * 512 + j], Wq[e * 512 + d], acc);
        Pc[((kc * 512) + j) * 32 + t] = f2bf(acc);
    } else {
        int i = (b - 1024) * 256 + (int)threadIdx.x;
        Wvb[i] = f2bf(Wv[i]);
    }
}

// ---------------- K2: fused main kernel. 1 block = 4 batches = 64 H rows.
// Phase 1: H f32 -> bf16 LDS (swizzled)           [barrier]
// Phase 2: T = Hbf @ M  (B-frags DIRECT from global/L2, reg dbuf, NO barriers)
//          T -> bf16 LDS                           [barrier]
// Phase 3: waves 0-3: scores+softmax+w ; waves 4-7: residual F-pool -> out
//                                                  [barrier]
// Phase 4: all waves: g = sum_k w[k] H[k,:] (bf16 from LDS) -> ws
__global__ __launch_bounds__(512) void attn_main_kernel(
    const float* __restrict__ H, const float* __restrict__ F,
    const unsigned short* __restrict__ Pc,
    float* __restrict__ out, unsigned short* __restrict__ g_ws)
{
    extern __shared__ char smem[];
    char* HBF = smem;                        // 64 rows x 1024B, swizzled (64 KB)
    char* TBF = smem + 65536;                // 64 rows x 1024B, swizzled (64 KB)
    float* wbuf = (float*)(smem + 131072);   // [4][16]

    const int tid = threadIdx.x;
    const int wv = tid >> 6;
    const int ln = tid & 63;
    const int rl = ln & 15;   // fragment row/col within tile
    const int kg = ln >> 4;   // k-group 0..3
    const long long gr0 = (long long)blockIdx.x * 64;

    // ---- Phase 1: stage H (fp32 global, coalesced) -> bf16 swizzled LDS
    {
        const float4* src = (const float4*)(H + gr0 * 512);
        #pragma unroll
        for (int rep = 0; rep < 16; ++rep) {
            int idx = rep * 512 + tid;                 // float4 index in [0,8192)
            float4 v = src[idx];
            ushort4 bv;
            bv.x = f2bf(v.x); bv.y = f2bf(v.y); bv.z = f2bf(v.z); bv.w = f2bf(v.w);
            unsigned byte = (unsigned)(idx >> 7) * 1024u + (unsigned)(idx & 127) * 8u;
            *(ushort4*)(HBF + swz1k(byte)) = bv;
        }
    }

    // B-fragment base (elements): Pc[((kc*512 + j)*32 + kg*8)], j = wv*64+jj*16+rl
    const unsigned short* bptr = Pc + ((wv * 64 + rl) * 32 + kg * 8);

    f32x4 acc[4][4];
    #pragma unroll
    for (int i = 0; i < 4; ++i)
        #pragma unroll
        for (int jj = 0; jj < 4; ++jj)
            acc[i][jj] = f32x4{0.f, 0.f, 0.f, 0.f};

    bf16x8 bcur[4];
    #pragma unroll
    for (int jj = 0; jj < 4; ++jj)
        bcur[jj] = *(const bf16x8*)(bptr + jj * 512);

    __syncthreads();   // HBF ready

    // ---- Phase 2: streaming GEMM, zero barriers
    #pragma unroll 2
    for (int kc = 0; kc < 16; ++kc) {
        bf16x8 bnext[4];
        if (kc < 15) {
            #pragma unroll
            for (int jj = 0; jj < 4; ++jj)
                bnext[jj] = *(const bf16x8*)(bptr + (kc + 1) * 16384 + jj * 512);
        }
        bf16x8 a[4];
        #pragma unroll
        for (int i = 0; i < 4; ++i) {
            unsigned off = (unsigned)(i * 16 + rl) * 1024u + (unsigned)kc * 64u + (unsigned)kg * 16u;
            a[i] = *(bf16x8*)(HBF + swz1k(off));
        }
        #pragma unroll
        for (int i = 0; i < 4; ++i)
            #pragma unroll
            for (int jj = 0; jj < 4; ++jj)
                acc[i][jj] = __builtin_amdgcn_mfma_f32_16x16x32_bf16(a[i], bcur[jj], acc[i][jj], 0, 0, 0);
        #pragma unroll
        for (int jj = 0; jj < 4; ++jj) bcur[jj] = bnext[jj];
    }

    // write T (bf16, swizzled rows) into TBF (C layout: row=kg*4+p, col=rl)
    #pragma unroll
    for (int i = 0; i < 4; ++i)
        #pragma unroll
        for (int jj = 0; jj < 4; ++jj)
            #pragma unroll
            for (int p = 0; p < 4; ++p) {
                unsigned row = (unsigned)(i * 16 + kg * 4 + p);
                unsigned col = (unsigned)(wv * 64 + jj * 16 + rl);
                *(unsigned short*)(TBF + swz1k(row * 1024u + col * 2u)) = f2bf(acc[i][jj][p]);
            }
    __syncthreads();

    // ---- Phase 3: waves 0-3: scores+softmax+w ; waves 4-7: residual pool
    if (wv < 4) {
        f32x4 sc = f32x4{0.f, 0.f, 0.f, 0.f};
        #pragma unroll
        for (int kc = 0; kc < 16; ++kc) {
            unsigned off = (unsigned)(wv * 16 + rl) * 1024u + (unsigned)kc * 64u + (unsigned)kg * 16u;
            bf16x8 aT = *(bf16x8*)(TBF + swz1k(off));
            bf16x8 bH = *(bf16x8*)(HBF + swz1k(off));   // H rows as B-operand == H^T
            sc = __builtin_amdgcn_mfma_f32_16x16x32_bf16(aT, bH, sc, 0, 0, 0);
        }
        const long long Bg = (long long)blockIdx.x * 4 + wv;
        const float* Fb = F + Bg * 16;
        float bias = logf(Fb[rl] + 1e-8f);              // bias for key column rl
        float alpha[4];
        #pragma unroll
        for (int p = 0; p < 4; ++p) {
            float s = sc[p] * 0.044194173824159216f + bias;  // 1/sqrt(512)
            float m = s;
            m = fmaxf(m, __shfl_xor(m, 8));
            m = fmaxf(m, __shfl_xor(m, 4));
            m = fmaxf(m, __shfl_xor(m, 2));
            m = fmaxf(m, __shfl_xor(m, 1));
            float e = expf(s - m);
            float sum = e;
            sum += __shfl_xor(sum, 8);
            sum += __shfl_xor(sum, 4);
            sum += __shfl_xor(sum, 2);
            sum += __shfl_xor(sum, 1);
            alpha[p] = e / sum;
        }
        float part = 0.f;
        #pragma unroll
        for (int p = 0; p < 4; ++p) part += Fb[kg * 4 + p] * alpha[p];
        part += __shfl_xor(part, 16);
        part += __shfl_xor(part, 32);
        if (ln < 16) wbuf[wv * 16 + ln] = part;
    } else {
        // residual F-pool: wave handles batch bb, lane handles 8 d-elems
        int bb = wv - 4;
        const long long Bg = (long long)blockIdx.x * 4 + bb;
        const float* Fb = F + Bg * 16;
        int d0 = ln * 8;
        float o[8];
        #pragma unroll
        for (int q = 0; q < 8; ++q) o[q] = 0.f;
        #pragma unroll
        for (int k = 0; k < 16; ++k) {
            unsigned off = (unsigned)(bb * 16 + k) * 1024u + (unsigned)d0 * 2u;
            ushort4 h0 = *(ushort4*)(HBF + swz1k(off));
            ushort4 h1 = *(ushort4*)(HBF + swz1k(off + 8u));
            float fk = Fb[k];
            o[0] = fmaf(fk, bf2f(h0.x), o[0]); o[1] = fmaf(fk, bf2f(h0.y), o[1]);
            o[2] = fmaf(fk, bf2f(h0.z), o[2]); o[3] = fmaf(fk, bf2f(h0.w), o[3]);
            o[4] = fmaf(fk, bf2f(h1.x), o[4]); o[5] = fmaf(fk, bf2f(h1.y), o[5]);
            o[6] = fmaf(fk, bf2f(h1.z), o[6]); o[7] = fmaf(fk, bf2f(h1.w), o[7]);
        }
        float4 oa; oa.x = o[0]; oa.y = o[1]; oa.z = o[2]; oa.w = o[3];
        float4 ob; ob.x = o[4]; ob.y = o[5]; ob.z = o[6]; ob.w = o[7];
        *(float4*)(out + Bg * 512 + d0) = oa;
        *(float4*)(out + Bg * 512 + d0 + 4) = ob;
    }
    __syncthreads();

    // ---- Phase 4: g (bf16). 8 waves = 4 batches x 2 d-halves, from LDS.
    {
        int bb = wv >> 1, dh = wv & 1;
        const long long Bg = (long long)blockIdx.x * 4 + bb;
        int d0 = dh * 256 + ln * 4;
        float g[4];
        #pragma unroll
        for (int q = 0; q < 4; ++q) g[q] = 0.f;
        #pragma unroll
        for (int k = 0; k < 16; ++k) {
            unsigned off = (unsigned)(bb * 16 + k) * 1024u + (unsigned)d0 * 2u;
            ushort4 h = *(ushort4*)(HBF + swz1k(off));
            float wk = wbuf[bb * 16 + k];
            g[0] = fmaf(wk, bf2f(h.x), g[0]); g[1] = fmaf(wk, bf2f(h.y), g[1]);
            g[2] = fmaf(wk, bf2f(h.z), g[2]); g[3] = fmaf(wk, bf2f(h.w), g[3]);
        }
        ushort4 g4; g4.x = f2bf(g[0]); g4.y = f2bf(g[1]); g4.z = f2bf(g[2]); g4.w = f2bf(g[3]);
        *(ushort4*)(g_ws + Bg * 512 + d0) = g4;
    }
}

// ---------------- K3: out += g @ Wv^T   (8192x512 @ 512x512, bf16 MFMA)
__global__ __launch_bounds__(256) void out_gemm_kernel(
    const unsigned short* __restrict__ g_ws,
    const unsigned short* __restrict__ Wvb,
    float* __restrict__ out)
{
    extern __shared__ char smem[];  // 32 KB: 32 rows x 1024B, swizzled
    const int tid = threadIdx.x;
    const int wv = tid >> 6, ln = tid & 63;
    const int rl = ln & 15, kg = ln >> 4;
    const long long r0 = (long long)blockIdx.x * 32;
    {
        const uint4* src = (const uint4*)(g_ws + r0 * 512);
        #pragma unroll
        for (int q = 0; q < 8; ++q) {
            int idx = q * 256 + tid;
            *(uint4*)(smem + swz1k((unsigned)idx * 16u)) = src[idx];
        }
    }
    __syncthreads();
    f32x4 acc[2][8];
    #pragma unroll
    for (int i = 0; i < 2; ++i)
        #pragma unroll
        for (int jj = 0; jj < 8; ++jj)
            acc[i][jj] = f32x4{0.f, 0.f, 0.f, 0.f};
    for (int kc = 0; kc < 16; ++kc) {
        bf16x8 a[2];
        #pragma unroll
        for (int i = 0; i < 2; ++i) {
            unsigned off = (unsigned)(i * 16 + rl) * 1024u + (unsigned)kc * 64u + (unsigned)kg * 16u;
            a[i] = *(bf16x8*)(smem + swz1k(off));
        }
        bf16x8 bfr[8];
        #pragma unroll
        for (int jj = 0; jj < 8; ++jj) {
            int n = wv * 128 + jj * 16 + rl;
            bfr[jj] = *(const bf16x8*)(Wvb + n * 512 + kc * 32 + kg * 8);  // Wv[n][k] row-major
        }
        #pragma unroll
        for (int i = 0; i < 2; ++i)
            #pragma unroll
            for (int jj = 0; jj < 8; ++jj)
                acc[i][jj] = __builtin_amdgcn_mfma_f32_16x16x32_bf16(a[i], bfr[jj], acc[i][jj], 0, 0, 0);
    }
    #pragma unroll
    for (int i = 0; i < 2; ++i)
        #pragma unroll
        for (int jj = 0; jj < 8; ++jj)
            #pragma unroll
            for (int p = 0; p < 4; ++p) {
                int row = i * 16 + kg * 4 + p;
                int col = wv * 128 + jj * 16 + rl;
                out[(r0 + row) * 512 + col] += acc[i][jj][p];
            }
}

extern "C" void kernel_launch(void* const* d_in, const int* in_sizes, int n_in,
                              void* d_out, int out_size, void* d_ws, size_t ws_size,
                              hipStream_t stream)
{
    const float* H  = (const float*)d_in[0];
    const float* F  = (const float*)d_in[1];
    const float* Wq = (const float*)d_in[2];
    const float* Wk = (const float*)d_in[3];
    const float* Wv = (const float*)d_in[4];
    float* out = (float*)d_out;

    unsigned short* Pc  = (unsigned short*)d_ws;       // 16*512*32   = 262144 bf16
    unsigned short* Wvb = Pc + 262144;                 // 512*512     = 262144 bf16
    unsigned short* g   = Wvb + 262144;                // 8192*512    = 4194304 bf16
    (void)in_sizes; (void)n_in; (void)out_size; (void)ws_size;

    hipLaunchKernelGGL(prep_kernel, dim3(2048), dim3(256), 0, stream, Wq, Wk, Wv, Pc, Wvb);
    hipLaunchKernelGGL(attn_main_kernel, dim3(2048), dim3(512), 131328, stream, H, F, Pc, out, g);
    hipLaunchKernelGGL(out_gemm_kernel, dim3(256), dim3(256), 32768, stream, g, Wvb, out);
}